// Round 17
// baseline (169.194 us; speedup 1.0000x reference)
//
#include <hip/hip_runtime.h>
#include <hip/hip_bf16.h>

// Problem constants (fixed by the reference)
#define BB 8      // batch
#define NQ 196    // image tokens (queries)
#define NKK 128   // sentence tokens (keys)
#define HH 8      // heads
#define DH 1024   // per-head dim
#define DI 1024   // image embed dim
#define DL 768    // sentence embed dim
#define HD 8192   // HH*DH
#define KSPLIT 8  // split-K factor for the out-projection GEMM
#define SSPLIT 4  // split-K factor for the score GEMM
#define MTOT (BB * NQ)          // 1568
#define CHK (MTOT * DH)         // 1605632: h-chunk stride for Qb'/ctx'/Oac
#define KVCHK (1024 * 1024)     // chunk stride for KVb' and WoT'

typedef __attribute__((ext_vector_type(8))) short short8;
typedef __attribute__((ext_vector_type(4))) float f32x4;

__device__ inline unsigned short f2bf(float f) {
  unsigned int x = __float_as_uint(f);
  unsigned int r = (x + 0x7fffu + ((x >> 16) & 1u)) >> 16;
  return (unsigned short)r;
}

// builtin async global->LDS (used by k_gemm3)
__device__ inline void gload16(const unsigned short* g, unsigned short* l) {
  __builtin_amdgcn_global_load_lds(
      (const __attribute__((address_space(1))) void*)g,
      (__attribute__((address_space(3))) void*)l, 16, 0, 0);
}

// LDS byte offset of a __shared__ pointer (addrspace(3) ptrtoint)
__device__ __attribute__((always_inline)) inline unsigned ldsOff(const unsigned short* p) {
  return (unsigned)(unsigned long long)
      (__attribute__((address_space(3))) const unsigned short*)p;
}

// raw-asm global->LDS (R12 win): invisible to compiler's memory model; only our
// counted vmcnt orders it. M0 = wave-uniform LDS byte base (HW adds lane*16).
__device__ __attribute__((always_inline)) inline void gload16a(
    const unsigned short* g, unsigned m0off) {
  unsigned s = __builtin_amdgcn_readfirstlane(m0off);
  asm volatile("s_mov_b32 m0, %1\n\t"
               "global_load_lds_dwordx4 %0, off"
               :: "v"(g), "s"(s) : "m0");
}

// ======== unified prep: 4 weight transposes + 2 input converts ========
__global__ __launch_bounds__(256) void k_prep(
    const float* __restrict__ Wq, const float* __restrict__ Wk,
    const float* __restrict__ Wv, const float* __restrict__ Wo,
    const float* __restrict__ img, const float* __restrict__ sent,
    unsigned short* __restrict__ WqT, unsigned short* __restrict__ WkvT,
    unsigned short* __restrict__ WoT,
    unsigned short* __restrict__ imgB, unsigned short* __restrict__ sentB) {
  int b = blockIdx.x, t = threadIdx.x;
  if (b >= 7168) {  // ---- converts: 2048 f32 per block ----
    const float* in; unsigned short* out; int i;
    if (b < 7952) { in = img;  out = imgB;  i = ((b - 7168) * 256 + t) * 8; }
    else          { in = sent; out = sentB; i = ((b - 7952) * 256 + t) * 8; }
    float4 x = *reinterpret_cast<const float4*>(in + i);
    float4 y = *reinterpret_cast<const float4*>(in + i + 4);
    short8 v;
    v[0] = (short)f2bf(x.x); v[1] = (short)f2bf(x.y);
    v[2] = (short)f2bf(x.z); v[3] = (short)f2bf(x.w);
    v[4] = (short)f2bf(y.x); v[5] = (short)f2bf(y.y);
    v[6] = (short)f2bf(y.z); v[7] = (short)f2bf(y.w);
    *reinterpret_cast<short8*>(out + i) = v;
    return;
  }
  const float* in; unsigned short* out; int R, C, bx; bool kcb = false;
  if (b < 2048)      { in = Wq; out = WqT;  R = DI; C = HD; bx = b; }
  else if (b < 3584) { in = Wk; out = WkvT; R = DL; C = HD; bx = b - 2048; }
  else if (b < 5120) { in = Wv; out = WkvT + (size_t)HD * DL; R = DL; C = HD; bx = b - 3584; }
  else               { in = Wo; out = WoT;  R = HD; C = DI; bx = b - 5120; kcb = true; }
  int nxc = C >> 6;
  int c0 = (bx % nxc) << 6, r0 = (bx / nxc) << 6;
  __shared__ float tile[64][65];
#pragma unroll
  for (int p = 0; p < 4; ++p) {
    int row = p * 16 + (t >> 4), c4 = (t & 15) << 2;
    float4 v = *reinterpret_cast<const float4*>(&in[(size_t)(r0 + row) * C + c0 + c4]);
    tile[row][c4] = v.x; tile[row][c4 + 1] = v.y;
    tile[row][c4 + 2] = v.z; tile[row][c4 + 3] = v.w;
  }
  __syncthreads();
#pragma unroll
  for (int p = 0; p < 2; ++p) {
    int cc = p * 32 + (t >> 3), r8 = (t & 7) << 3;
    short8 w;
#pragma unroll
    for (int j = 0; j < 8; ++j) w[j] = (short)f2bf(tile[r8 + j][cc]);
    size_t off;
    if (kcb)
      off = ((size_t)(r0 >> 10) << 20) + (size_t)(c0 + cc) * 1024 + (r0 & 1023) + r8;
    else
      off = (size_t)(c0 + cc) * R + r0 + r8;
    *reinterpret_cast<short8*>(&out[off]) = w;
  }
}

// ================= 256x256 8-phase MFMA GEMM — even-stage, ASM staging =================

__device__ __attribute__((always_inline)) inline void ph_pre() {
  __builtin_amdgcn_s_barrier();
  asm volatile("s_waitcnt lgkmcnt(0)" ::: "memory");
  __builtin_amdgcn_sched_barrier(0);    // rule #18
  __builtin_amdgcn_s_setprio(1);
}
__device__ __attribute__((always_inline)) inline void ph_post() {
  __builtin_amdgcn_s_setprio(0);
  __builtin_amdgcn_s_barrier();
}
__device__ __attribute__((always_inline)) inline void ph_post_vm4() {
  __builtin_amdgcn_s_setprio(0);
  asm volatile("s_waitcnt vmcnt(4)" ::: "memory");
  __builtin_amdgcn_s_barrier();
}
__device__ __attribute__((always_inline)) inline void ph_post_vm0() {
  __builtin_amdgcn_s_setprio(0);
  asm volatile("s_waitcnt vmcnt(0)" ::: "memory");
  __builtin_amdgcn_s_barrier();
}

#define LDA8(d, buf, s)                                                          \
  { _Pragma("unroll") for (int mi = 0; mi < 4; ++mi) {                           \
      const int row_ = wm * 128 + (s) * 64 + mi * 16 + fr;                       \
      d[mi][0] = *reinterpret_cast<const short8*>(&As[buf][row_ * 64 + swz0]);   \
      d[mi][1] = *reinterpret_cast<const short8*>(&As[buf][row_ * 64 + swz1]);   \
    } }
#define LDB8(d, buf, s)                                                          \
  { _Pragma("unroll") for (int ni = 0; ni < 2; ++ni) {                           \
      const int row_ = wn * 64 + (s) * 32 + ni * 16 + fr;                        \
      d[ni][0] = *reinterpret_cast<const short8*>(&Bs[buf][row_ * 64 + swz0]);   \
      d[ni][1] = *reinterpret_cast<const short8*>(&Bs[buf][row_ * 64 + swz1]);   \
    } }
#define MMQ(a, sa, b, sb)                                                        \
  { _Pragma("unroll") for (int kk = 0; kk < 2; ++kk) {                           \
      _Pragma("unroll") for (int mi = 0; mi < 4; ++mi) {                         \
        _Pragma("unroll") for (int ni = 0; ni < 2; ++ni)                         \
          acc[(sa) * 4 + mi][(sb) * 2 + ni] =                                    \
              __builtin_amdgcn_mfma_f32_16x16x32_bf16(                           \
                  a[mi][kk], b[ni][kk], acc[(sa) * 4 + mi][(sb) * 2 + ni], 0, 0, 0); \
      } } }
// staging via raw asm; LDS offsets precomputed per wave (aL/bL bases, bytes)
#define STA8(buf, h, kof)                                                        \
  { gload16a(aS[h][0] + (kof), aL + (buf) * 32768 + (h) * 16384);                \
    gload16a(aS[h][1] + (kof), aL + (buf) * 32768 + (h) * 16384 + 8192); }
#define STB8(buf, h, kof)                                                        \
  { gload16a(bS[h][0] + (kof), bL + (buf) * 32768 + (h) * 16384);                \
    gload16a(bS[h][1] + (kof), bL + (buf) * 32768 + (h) * 16384 + 8192); }

struct GCfg {
  const unsigned short* A; const unsigned short* B; void* C;
  int M, K, lda, ldb, ldc, nx, ny;
  long aKC, bKC, cKC;   // split-K / batch chunk strides
};

// HB: C h-chunked by column. PVF: kc = bh batch index, C = ctx' h-chunk layout.
template<bool C_BF16, bool HB, bool PVF>
__global__ __launch_bounds__(512, 2) void k_gemm8(GCfg c0, GCfg c1, int split) {
  __shared__ unsigned short As[2][16384];   // 2 bufs x 256x64 bf16
  __shared__ unsigned short Bs[2][16384];

  const int seg = (int)blockIdx.x >= split;
  const GCfg cfg = seg ? c1 : c0;
  const int o = (int)blockIdx.x - (seg ? split : 0);
  const int nseg = seg ? ((int)gridDim.x - split) : split;
  const int qq = nseg >> 3;
  const int g = (o & 7) * qq + (o >> 3);
  const int ybl = g % cfg.ny; int t1 = g / cfg.ny;
  const int xbl = t1 % cfg.nx; const int kc = t1 / cfg.nx;

  const int M = cfg.M, lda = cfg.lda, ldb = cfg.ldb;
  const unsigned short* Ab = cfg.A + (size_t)kc * cfg.aKC;
  const unsigned short* Bb = cfg.B + (size_t)kc * cfg.bKC;

  const int tid = threadIdx.x, lane = tid & 63, wid = tid >> 6;  // 8 waves
  const int wm = wid >> 2, wn = wid & 3;
  const int m_base = ybl * 256, n_base = xbl * 256;
  const int fr = lane & 15, qk = lane >> 4;
  const int swz0 = ((qk ^ (fr & 7)) << 3);
  const int swz1 = (((4 + qk) ^ (fr & 7)) << 3);

  const int srow = lane >> 3;
  const int sc8 = (((lane & 7) ^ srow) << 3);
  const unsigned short* aS[2][2];
  const unsigned short* bS[2][2];
#pragma unroll
  for (int h = 0; h < 2; ++h)
#pragma unroll
    for (int j = 0; j < 2; ++j) {
      int rm = m_base + h * 128 + j * 64 + wid * 8 + srow;
      rm = rm < M ? rm : M - 1;                       // clamp; clamped rows never stored
      aS[h][j] = Ab + (size_t)rm * lda + sc8;
      bS[h][j] = Bb + (size_t)(n_base + h * 128 + j * 64 + wid * 8 + srow) * ldb + sc8;
    }
  // LDS byte bases for this wave's staging slots (wave-uniform)
  const unsigned aL = ldsOff(&As[0][0]) + (unsigned)(wid * 1024);
  const unsigned bL = ldsOff(&Bs[0][0]) + (unsigned)(wid * 1024);

  short8 a0[4][2], a1[4][2], b0[2][2], b1[2][2];
  f32x4 acc[8][4] = {};

  const int NT = cfg.K >> 6;    // K-tiles (even, >= 2)
  const int NIT = NT >> 1;      // tile pairs

  // ---- prologue: B(t0), A(t0) -> buf0; B(t1) -> buf1. 12 issues; drain 8 oldest ----
  STB8(0, 0, 0) STB8(0, 1, 0) STA8(0, 0, 0) STA8(0, 1, 0)
  STB8(1, 0, 64) STB8(1, 1, 64)
  asm volatile("s_waitcnt vmcnt(4)" ::: "memory");
  __builtin_amdgcn_s_barrier();

  // ---- main loop: exactly 2 gloads per phase; vmcnt(4) at ph4/ph8 ----
  for (int it = 0; it < NIT - 1; ++it) {
    const int t1k = (2 * it + 1) << 6;
    const int t2k = (2 * it + 2) << 6;
    const int t3k = (2 * it + 3) << 6;
    LDA8(a0, 0, 0) LDB8(b0, 0, 0) STA8(1, 0, t1k)
    ph_pre(); MMQ(a0, 0, b0, 0) ph_post();
    LDB8(b1, 0, 1) STA8(1, 1, t1k)
    ph_pre(); MMQ(a0, 0, b1, 1) ph_post();
    LDA8(a1, 0, 1) STB8(0, 0, t2k)
    ph_pre(); MMQ(a1, 1, b1, 1) ph_post();
    STB8(0, 1, t2k)
    ph_pre(); MMQ(a1, 1, b0, 0) ph_post_vm4();
    LDA8(a0, 1, 0) LDB8(b0, 1, 0) STA8(0, 0, t2k)
    ph_pre(); MMQ(a0, 0, b0, 0) ph_post();
    LDB8(b1, 1, 1) STA8(0, 1, t2k)
    ph_pre(); MMQ(a0, 0, b1, 1) ph_post();
    LDA8(a1, 1, 1) STB8(1, 0, t3k)
    ph_pre(); MMQ(a1, 1, b1, 1) ph_post();
    STB8(1, 1, t3k)
    ph_pre(); MMQ(a1, 1, b0, 0) ph_post_vm4();
  }

  // ---- peeled final pair (also the whole loop when NT==2) ----
  {
    const int tlk = (NT - 1) << 6;
    LDA8(a0, 0, 0) LDB8(b0, 0, 0) STA8(1, 0, tlk)
    ph_pre(); MMQ(a0, 0, b0, 0) ph_post();
    LDB8(b1, 0, 1) STA8(1, 1, tlk)
    ph_pre(); MMQ(a0, 0, b1, 1) ph_post();
    LDA8(a1, 0, 1)
    ph_pre(); MMQ(a1, 1, b1, 1) ph_post();
    ph_pre(); MMQ(a1, 1, b0, 0) ph_post_vm0();       // all staging landed
    LDA8(a0, 1, 0) LDB8(b0, 1, 0)
    ph_pre(); MMQ(a0, 0, b0, 0) ph_post();
    LDB8(b1, 1, 1)
    ph_pre(); MMQ(a0, 0, b1, 1) ph_post();
    LDA8(a1, 1, 1)
    ph_pre(); MMQ(a1, 1, b1, 1) ph_post();
    ph_pre(); MMQ(a1, 1, b0, 0)
    __builtin_amdgcn_s_setprio(0);
  }

  // ---- epilogue ----
  const size_t cOff = (size_t)kc * cfg.cKC;
  const int ldc = cfg.ldc;
  const int rq4 = qk * 4;
#pragma unroll
  for (int mi = 0; mi < 8; ++mi) {
#pragma unroll
    for (int ni = 0; ni < 4; ++ni) {
      int col = n_base + wn * 64 + ni * 16 + fr;
#pragma unroll
      for (int i = 0; i < 4; ++i) {
        int row = m_base + wm * 128 + mi * 16 + rq4 + i;
        if (row < M) {
          float val = acc[mi][ni][i];
          size_t off;
          if constexpr (PVF)       // ctx'[h=kc&7][(b=kc>>3)*NQ + row][col]
            off = (size_t)(kc & 7) * cfg.cKC
                + ((size_t)(kc >> 3) * NQ + row) * 1024 + col;
          else if constexpr (HB)
            off = (size_t)(col >> 10) * cfg.cKC + (size_t)row * ldc + (col & 1023);
          else
            off = cOff + (size_t)row * ldc + col;
          if constexpr (C_BF16) ((unsigned short*)cfg.C)[off] = f2bf(val);
          else                  ((float*)cfg.C)[off] = val;
        }
      }
    }
  }
}

// ---------- 128x128 single-buffer engine (score) — builtin gload ----------
template<bool C_BF16>
__global__ __launch_bounds__(256, 2) void k_gemm3(
    const unsigned short* __restrict__ A, const unsigned short* __restrict__ B,
    void* __restrict__ Cptr,
    int M, int K, int lda, int ldb, int ldc,
    int nx, int ny, int ZBH,
    long aSB, long aSH, long bSB, long bSH, long cSB, long cSH,
    long aKC, long bKC, long cKC) {
  __shared__ unsigned short As[8192];
  __shared__ unsigned short Bs[8192];

  const int nblk = gridDim.x;
  const int qq = nblk >> 3, rr = nblk & 7;
  int g;
  { const int o = blockIdx.x, xcd = o & 7, i = o >> 3;
    g = (xcd < rr ? xcd * (qq + 1) : rr * (qq + 1) + (xcd - rr) * qq) + i; }
  const int ybl = g % ny; int t1 = g / ny;
  const int xbl = t1 % nx; const int zz = t1 / nx;
  const int kc = zz / ZBH, bh = zz % ZBH;
  const int zb = bh >> 3, zh = bh & 7;

  const unsigned short* Ab = A + (size_t)zb * aSB + (size_t)zh * aSH + (size_t)kc * aKC;
  const unsigned short* Bb = B + (size_t)zb * bSB + (size_t)zh * bSH + (size_t)kc * bKC;

  const int tid = threadIdx.x, lane = tid & 63, wid = tid >> 6;
  const int wm = wid >> 1, wn = wid & 1;
  const int m_base = ybl * 128, n_base = xbl * 128;

  const int r0 = wid * 32 + (lane >> 3);
  const int sc8 = (((lane & 7) ^ (lane >> 3)) << 3);
  const unsigned short* aSrc[4];
  const unsigned short* bSrc[4];
#pragma unroll
  for (int p = 0; p < 4; ++p) {
    int rm = m_base + r0 + p * 8; rm = rm < M ? rm : M - 1;
    aSrc[p] = Ab + (size_t)rm * lda + sc8;
    bSrc[p] = Bb + (size_t)(n_base + r0 + p * 8) * ldb + sc8;
  }

  const int fr = lane & 15;
  const int qk = lane >> 4;
  f32x4 acc[4][4] = {};

  for (int k0 = 0; k0 < K; k0 += 64) {
#pragma unroll
    for (int p = 0; p < 4; ++p) gload16(aSrc[p] + k0, &As[wid * 2048 + p * 512]);
#pragma unroll
    for (int p = 0; p < 4; ++p) gload16(bSrc[p] + k0, &Bs[wid * 2048 + p * 512]);
    __syncthreads();
#pragma unroll
    for (int kk = 0; kk < 2; ++kk) {
      short8 af[4], bfr[4];
#pragma unroll
      for (int mi = 0; mi < 4; ++mi) {
        int row = wm * 64 + mi * 16 + fr;
        int swz = ((kk * 4 + qk) ^ (row & 7)) << 3;
        af[mi] = *reinterpret_cast<const short8*>(&As[row * 64 + swz]);
      }
#pragma unroll
      for (int ni = 0; ni < 4; ++ni) {
        int row = wn * 64 + ni * 16 + fr;
        int swz = ((kk * 4 + qk) ^ (row & 7)) << 3;
        bfr[ni] = *reinterpret_cast<const short8*>(&Bs[row * 64 + swz]);
      }
#pragma unroll
      for (int mi = 0; mi < 4; ++mi)
#pragma unroll
        for (int ni = 0; ni < 4; ++ni)
          acc[mi][ni] = __builtin_amdgcn_mfma_f32_16x16x32_bf16(af[mi], bfr[ni], acc[mi][ni], 0, 0, 0);
    }
    __syncthreads();
  }

  const size_t cOff = (size_t)zb * cSB + (size_t)zh * cSH + (size_t)kc * cKC;
  const int rq = qk * 4;
#pragma unroll
  for (int mi = 0; mi < 4; ++mi) {
#pragma unroll
    for (int ni = 0; ni < 4; ++ni) {
      int col = n_base + wn * 64 + ni * 16 + fr;
#pragma unroll
      for (int i = 0; i < 4; ++i) {
        int row = m_base + wm * 64 + mi * 16 + rq + i;
        if (row < M) {
          float val = acc[mi][ni][i];
          size_t off = cOff + (size_t)row * ldc + col;
          if constexpr (C_BF16) ((unsigned short*)Cptr)[off] = f2bf(val);
          else                  ((float*)Cptr)[off] = val;
        }
      }
    }
  }
}

// ======== fused midsection: V-transpose (blocks [0,8192)) + masked softmax ========
#define S_PART ((size_t)64 * NQ * NKK)
__global__ __launch_bounds__(256) void k_mid(
    const unsigned short* __restrict__ Vbase, unsigned short* __restrict__ Vt,
    const float* __restrict__ S, unsigned short* __restrict__ P,
    const int* __restrict__ mask) {
  __shared__ unsigned short tile[32][34];
  int blk = blockIdx.x;
  if (blk < 8192) {
    // ---- V transpose: KVb' V-chunk [8+h][b*128+key][1024 d] -> Vt[bh][d][key] ----
    int z = blk >> 7, b = z >> 3, h = z & 7;
    int d0 = (blk & 31) * 32, k0 = ((blk >> 5) & 3) * 32;
    const unsigned short* in = Vbase + ((size_t)h << 20) + (size_t)b * NKK * 1024;
    unsigned short* out = Vt + (size_t)z * DH * NKK;
    {
      int rr = threadIdx.x >> 3, c4 = (threadIdx.x & 7) << 2;
      ushort4 v = *reinterpret_cast<const ushort4*>(&in[(size_t)(k0 + rr) * 1024 + d0 + c4]);
      tile[rr][c4] = v.x; tile[rr][c4 + 1] = v.y;
      tile[rr][c4 + 2] = v.z; tile[rr][c4 + 3] = v.w;
    }
    __syncthreads();
    {
      int cc = threadIdx.x >> 3, r4 = (threadIdx.x & 7) << 2;
      ushort4 w;
      w.x = tile[r4][cc];     w.y = tile[r4 + 1][cc];
      w.z = tile[r4 + 2][cc]; w.w = tile[r4 + 3][cc];
      *reinterpret_cast<ushort4*>(&out[(size_t)(d0 + cc) * NKK + k0 + r4]) = w;
    }
    return;
  }
  // ---- masked softmax over 128 keys (reduces SSPLIT split-K partials), 1 wave/row ----
  int row = (blk - 8192) * 4 + (threadIdx.x >> 6);
  if (row >= BB * HH * NQ) return;
  int lane = threadIdx.x & 63;
  int b = row / (HH * NQ);
  const float* s = S + (size_t)row * NKK;
  float s0 = 0.f, s1 = 0.f;
#pragma unroll
  for (int k = 0; k < SSPLIT; ++k) {
    s0 += s[lane + k * S_PART];
    s1 += s[lane + 64 + k * S_PART];
  }
  s0 *= 0.03125f; s1 *= 0.03125f;
  const int* mrow = mask + b * NKK;
  if (mrow[lane] == 0)      s0 = -1e30f;
  if (mrow[lane + 64] == 0) s1 = -1e30f;
  float mx = fmaxf(s0, s1);
#pragma unroll
  for (int d = 32; d; d >>= 1) mx = fmaxf(mx, __shfl_xor(mx, d));
  float e0 = __expf(s0 - mx), e1 = __expf(s1 - mx);
  float sum = e0 + e1;
#pragma unroll
  for (int d = 32; d; d >>= 1) sum += __shfl_xor(sum, d);
  float inv = 1.0f / sum;
  P[(size_t)row * NKK + lane]      = f2bf(e0 * inv);
  P[(size_t)row * NKK + lane + 64] = f2bf(e1 * inv);
}

// --- fused split-K reduce (bf16 partials) + residual + LayerNorm over 1024, 1 block/row ---
__global__ __launch_bounds__(256) void k_layernorm_red(
    const unsigned short* __restrict__ Parts, const float* __restrict__ resid,
    const float* __restrict__ gamma, const float* __restrict__ beta,
    float* __restrict__ out, int M) {
  int row = blockIdx.x;
  int tid = threadIdx.x;
  const size_t stride = (size_t)M * DI;
  const unsigned short* p = Parts + (size_t)row * DI;
  const float* r = resid + (size_t)row * DI;
  float v[4], sum = 0.f, sq = 0.f;
#pragma unroll
  for (int i = 0; i < 4; ++i) {
    int c = tid + i * 256;
    float acc = r[c];
#pragma unroll
    for (int k = 0; k < KSPLIT; ++k)
      acc += __uint_as_float((unsigned)p[k * stride + c] << 16);
    v[i] = acc; sum += acc; sq += acc * acc;
  }
#pragma unroll
  for (int d = 32; d; d >>= 1) { sum += __shfl_xor(sum, d); sq += __shfl_xor(sq, d); }
  __shared__ float ssum[4], ssq[4];
  int w = tid >> 6;
  if ((tid & 63) == 0) { ssum[w] = sum; ssq[w] = sq; }
  __syncthreads();
  sum = ssum[0] + ssum[1] + ssum[2] + ssum[3];
  sq  = ssq[0]  + ssq[1]  + ssq[2]  + ssq[3];
  float mean = sum * (1.0f / DI);
  float var  = sq * (1.0f / DI) - mean * mean;
  float rstd = rsqrtf(var + 1e-5f);
  float* o = out + (size_t)row * DI;
#pragma unroll
  for (int i = 0; i < 4; ++i) {
    int c = tid + i * 256;
    o[c] = (v[i] - mean) * rstd * gamma[c] + beta[c];
  }
}

extern "C" void kernel_launch(void* const* d_in, const int* in_sizes, int n_in,
                              void* d_out, int out_size, void* d_ws, size_t ws_size,
                              hipStream_t stream) {
  const float* img   = (const float*)d_in[0];
  const float* sent  = (const float*)d_in[1];
  const int*   mask  = (const int*)d_in[2];
  const float* Wq    = (const float*)d_in[3];
  const float* Wk    = (const float*)d_in[4];
  const float* Wv    = (const float*)d_in[5];
  const float* Wo    = (const float*)d_in[6];
  const float* gamma = (const float*)d_in[7];
  const float* beta  = (const float*)d_in[8];
  float* out = (float*)d_out;

  // ---- workspace map (lifetime-aliased; ws = 256 MB) ----
  // Qb'[8 h][1568][1024] | KVb'[16 chunk][1024][1024] | WoT'[8 kc][1024][1024]
  // ctx'[8 h][1568][1024] | Oac[8 kc][1568][1024] bf16
  // S2[4 kc][64 bh][196][128] f32 and P at high addresses (no aliasing)
  char* ws = (char*)d_ws;
  unsigned short* WoT   = (unsigned short*)(ws);                  // s0-s7
  unsigned short* WkvT  = (unsigned short*)(ws + 16777216);       // s0-s2
  unsigned short* Vt    = (unsigned short*)(ws + 16777216);       // s5-s6 (over WkvT)
  unsigned short* Oac   = (unsigned short*)(ws + 16777216);       // s7-s8 (25.7 MB bf16)
  unsigned short* Qb    = (unsigned short*)(ws + 49610752);       // s1-s4
  unsigned short* KVb   = (unsigned short*)(ws + 75300864);       // s2-s5
  unsigned short* ctx   = (unsigned short*)(ws + 75300864);       // s6-s7
  unsigned short* WqT   = (unsigned short*)(ws + 75300864);       // s0-s1
  unsigned short* imgB  = (unsigned short*)(ws + 92078080);       // s0-s1
  unsigned short* sentB = (unsigned short*)(ws + 108855296);      // s0-s2
  float*          S2    = (float*)         (ws + 134217728);      // s4-s5 (25.7 MB)
  unsigned short* P     = (unsigned short*)(ws + 167772160);      // s5-s6 (3.2 MB)

  dim3 tb(256);
  dim3 tb8(512);

  // s0) all transposes + input converts, one launch (WoT kc-blocked)
  k_prep<<<dim3(8336), tb, 0, stream>>>(Wq, Wk, Wv, Wo, img, sent,
                                        WqT, WkvT, WoT, imgB, sentB);

  // s1+s2) Q-proj (HB -> Qb') and KV-proj (HB -> KVb'), one launch
  GCfg cfgQ  = { imgB,  WqT,  Qb,  MTOT,     DI, DI, DI, 1024, 32, 7, 0, 0, (long)CHK };
  GCfg cfgKV = { sentB, WkvT, KVb, BB * NKK, DL, DL, DL, 1024, 64, 4, 0, 0, (long)KVCHK };
  k_gemm8<true, true, false><<<dim3(224 + 256), tb8, 0, stream>>>(cfgQ, cfgKV, 224);

  // s4) S2[kc][b][h][196][128] = Q_bh[:,kc] @ K_bh[:,kc]^T  (split-K=4, 512 blocks = 2/CU)
  k_gemm3<false><<<dim3(2 * 1 * SSPLIT * 64), tb, 0, stream>>>(
      Qb, KVb, S2, NQ, DH / SSPLIT, 1024, 1024, NKK,
      1, 2, 64,
      (long)NQ * 1024, (long)CHK,
      (long)NKK * 1024, (long)KVCHK,
      (long)HH * NQ * NKK, (long)NQ * NKK,
      (long)(DH / SSPLIT), (long)(DH / SSPLIT), (long)64 * NQ * NKK);

  // s5) fused: V -> Vt transpose (8192 blocks) + P = softmax(sum(S2)/32) (3136 blocks)
  k_mid<<<dim3(8192 + (BB * HH * NQ) / 4), tb, 0, stream>>>(
      KVb + ((size_t)8 << 20), Vt, S2, P, mask);

  // s6) ctx'[h][b*196+q][1024] = P_bh @ V_bh  — gemm8 PVF path, 256 blocks, NT=2
  GCfg cfgPV = { P, Vt, ctx, NQ, NKK, NKK, NKK, 1024, 4, 1,
                 (long)NQ * NKK, (long)DH * NKK, (long)CHK };
  k_gemm8<true, false, true><<<dim3(256), tb8, 0, stream>>>(cfgPV, cfgPV, 256);

  // s7) out-proj split-K: Oac[kc] = ctx'[kc] @ WoT'[kc]^T  — bf16 partials
  GCfg cfgO = { ctx, WoT, Oac, MTOT, HD / KSPLIT, 1024, 1024, DI, 4, 7,
                (long)CHK, (long)KVCHK, (long)CHK };
  k_gemm8<true, false, false><<<dim3(224), tb8, 0, stream>>>(cfgO, cfgO, 224);

  // s8) fused reduce(8 bf16 partials) + residual + LayerNorm -> d_out
  k_layernorm_red<<<dim3(BB * NQ), tb, 0, stream>>>(Oac, img, gamma, beta, out, BB * NQ);
}

// Round 18
// 167.667 us; speedup vs baseline: 1.0091x; 1.0091x over previous
//
#include <hip/hip_runtime.h>
#include <hip/hip_bf16.h>

// Problem constants (fixed by the reference)
#define BB 8      // batch
#define NQ 196    // image tokens (queries)
#define NKK 128   // sentence tokens (keys)
#define HH 8      // heads
#define DH 1024   // per-head dim
#define DI 1024   // image embed dim
#define DL 768    // sentence embed dim
#define HD 8192   // HH*DH
#define KSPLIT 8  // split-K factor for the out-projection GEMM
#define MTOT (BB * NQ)          // 1568
#define CHK (MTOT * DH)         // 1605632: h-chunk stride for Qb'/ctx'/Oac
#define KVCHK (1024 * 1024)     // chunk stride for KVb' and WoT'

typedef __attribute__((ext_vector_type(8))) short short8;
typedef __attribute__((ext_vector_type(4))) float f32x4;

__device__ inline unsigned short f2bf(float f) {
  unsigned int x = __float_as_uint(f);
  unsigned int r = (x + 0x7fffu + ((x >> 16) & 1u)) >> 16;
  return (unsigned short)r;
}

// builtin async global->LDS (used by k_gemm3)
__device__ inline void gload16(const unsigned short* g, unsigned short* l) {
  __builtin_amdgcn_global_load_lds(
      (const __attribute__((address_space(1))) void*)g,
      (__attribute__((address_space(3))) void*)l, 16, 0, 0);
}

// LDS byte offset of a __shared__ pointer (addrspace(3) ptrtoint)
__device__ __attribute__((always_inline)) inline unsigned ldsOff(const unsigned short* p) {
  return (unsigned)(unsigned long long)
      (__attribute__((address_space(3))) const unsigned short*)p;
}

// raw-asm global->LDS (R12 win): invisible to compiler's memory model; only our
// counted vmcnt orders it. M0 = wave-uniform LDS byte base (HW adds lane*16).
__device__ __attribute__((always_inline)) inline void gload16a(
    const unsigned short* g, unsigned m0off) {
  unsigned s = __builtin_amdgcn_readfirstlane(m0off);
  asm volatile("s_mov_b32 m0, %1\n\t"
               "global_load_lds_dwordx4 %0, off"
               :: "v"(g), "s"(s) : "m0");
}

// ======== unified prep: 4 weight transposes + 2 input converts ========
__global__ __launch_bounds__(256) void k_prep(
    const float* __restrict__ Wq, const float* __restrict__ Wk,
    const float* __restrict__ Wv, const float* __restrict__ Wo,
    const float* __restrict__ img, const float* __restrict__ sent,
    unsigned short* __restrict__ WqT, unsigned short* __restrict__ WkvT,
    unsigned short* __restrict__ WoT,
    unsigned short* __restrict__ imgB, unsigned short* __restrict__ sentB) {
  int b = blockIdx.x, t = threadIdx.x;
  if (b >= 7168) {  // ---- converts: 2048 f32 per block ----
    const float* in; unsigned short* out; int i;
    if (b < 7952) { in = img;  out = imgB;  i = ((b - 7168) * 256 + t) * 8; }
    else          { in = sent; out = sentB; i = ((b - 7952) * 256 + t) * 8; }
    float4 x = *reinterpret_cast<const float4*>(in + i);
    float4 y = *reinterpret_cast<const float4*>(in + i + 4);
    short8 v;
    v[0] = (short)f2bf(x.x); v[1] = (short)f2bf(x.y);
    v[2] = (short)f2bf(x.z); v[3] = (short)f2bf(x.w);
    v[4] = (short)f2bf(y.x); v[5] = (short)f2bf(y.y);
    v[6] = (short)f2bf(y.z); v[7] = (short)f2bf(y.w);
    *reinterpret_cast<short8*>(out + i) = v;
    return;
  }
  const float* in; unsigned short* out; int R, C, bx; bool kcb = false;
  if (b < 2048)      { in = Wq; out = WqT;  R = DI; C = HD; bx = b; }
  else if (b < 3584) { in = Wk; out = WkvT; R = DL; C = HD; bx = b - 2048; }
  else if (b < 5120) { in = Wv; out = WkvT + (size_t)HD * DL; R = DL; C = HD; bx = b - 3584; }
  else               { in = Wo; out = WoT;  R = HD; C = DI; bx = b - 5120; kcb = true; }
  int nxc = C >> 6;
  int c0 = (bx % nxc) << 6, r0 = (bx / nxc) << 6;
  __shared__ float tile[64][65];
#pragma unroll
  for (int p = 0; p < 4; ++p) {
    int row = p * 16 + (t >> 4), c4 = (t & 15) << 2;
    float4 v = *reinterpret_cast<const float4*>(&in[(size_t)(r0 + row) * C + c0 + c4]);
    tile[row][c4] = v.x; tile[row][c4 + 1] = v.y;
    tile[row][c4 + 2] = v.z; tile[row][c4 + 3] = v.w;
  }
  __syncthreads();
#pragma unroll
  for (int p = 0; p < 2; ++p) {
    int cc = p * 32 + (t >> 3), r8 = (t & 7) << 3;
    short8 w;
#pragma unroll
    for (int j = 0; j < 8; ++j) w[j] = (short)f2bf(tile[r8 + j][cc]);
    size_t off;
    if (kcb)
      off = ((size_t)(r0 >> 10) << 20) + (size_t)(c0 + cc) * 1024 + (r0 & 1023) + r8;
    else
      off = (size_t)(c0 + cc) * R + r0 + r8;
    *reinterpret_cast<short8*>(&out[off]) = w;
  }
}

// ================= 256x256 8-phase MFMA GEMM — even-stage, ASM staging =================

__device__ __attribute__((always_inline)) inline void ph_pre() {
  __builtin_amdgcn_s_barrier();
  asm volatile("s_waitcnt lgkmcnt(0)" ::: "memory");
  __builtin_amdgcn_sched_barrier(0);    // rule #18
  __builtin_amdgcn_s_setprio(1);
}
__device__ __attribute__((always_inline)) inline void ph_post() {
  __builtin_amdgcn_s_setprio(0);
  __builtin_amdgcn_s_barrier();
}
__device__ __attribute__((always_inline)) inline void ph_post_vm4() {
  __builtin_amdgcn_s_setprio(0);
  asm volatile("s_waitcnt vmcnt(4)" ::: "memory");
  __builtin_amdgcn_s_barrier();
}
__device__ __attribute__((always_inline)) inline void ph_post_vm0() {
  __builtin_amdgcn_s_setprio(0);
  asm volatile("s_waitcnt vmcnt(0)" ::: "memory");
  __builtin_amdgcn_s_barrier();
}

#define LDA8(d, buf, s)                                                          \
  { _Pragma("unroll") for (int mi = 0; mi < 4; ++mi) {                           \
      const int row_ = wm * 128 + (s) * 64 + mi * 16 + fr;                       \
      d[mi][0] = *reinterpret_cast<const short8*>(&As[buf][row_ * 64 + swz0]);   \
      d[mi][1] = *reinterpret_cast<const short8*>(&As[buf][row_ * 64 + swz1]);   \
    } }
#define LDB8(d, buf, s)                                                          \
  { _Pragma("unroll") for (int ni = 0; ni < 2; ++ni) {                           \
      const int row_ = wn * 64 + (s) * 32 + ni * 16 + fr;                        \
      d[ni][0] = *reinterpret_cast<const short8*>(&Bs[buf][row_ * 64 + swz0]);   \
      d[ni][1] = *reinterpret_cast<const short8*>(&Bs[buf][row_ * 64 + swz1]);   \
    } }
#define MMQ(a, sa, b, sb)                                                        \
  { _Pragma("unroll") for (int kk = 0; kk < 2; ++kk) {                           \
      _Pragma("unroll") for (int mi = 0; mi < 4; ++mi) {                         \
        _Pragma("unroll") for (int ni = 0; ni < 2; ++ni)                         \
          acc[(sa) * 4 + mi][(sb) * 2 + ni] =                                    \
              __builtin_amdgcn_mfma_f32_16x16x32_bf16(                           \
                  a[mi][kk], b[ni][kk], acc[(sa) * 4 + mi][(sb) * 2 + ni], 0, 0, 0); \
      } } }
// staging via raw asm; LDS offsets precomputed per wave (aL/bL bases, bytes)
#define STA8(buf, h, kof)                                                        \
  { gload16a(aS[h][0] + (kof), aL + (buf) * 32768 + (h) * 16384);                \
    gload16a(aS[h][1] + (kof), aL + (buf) * 32768 + (h) * 16384 + 8192); }
#define STB8(buf, h, kof)                                                        \
  { gload16a(bS[h][0] + (kof), bL + (buf) * 32768 + (h) * 16384);                \
    gload16a(bS[h][1] + (kof), bL + (buf) * 32768 + (h) * 16384 + 8192); }

struct GCfg {
  const unsigned short* A; const unsigned short* B; void* C;
  int M, K, lda, ldb, ldc, nx, ny;
  long aKC, bKC, cKC;   // split-K / batch chunk strides
};

// HB: C h-chunked by column. PVF: kc = bh batch index, C = ctx' h-chunk layout.
template<bool C_BF16, bool HB, bool PVF>
__global__ __launch_bounds__(512, 2) void k_gemm8(GCfg c0, GCfg c1, int split) {
  __shared__ unsigned short As[2][16384];   // 2 bufs x 256x64 bf16
  __shared__ unsigned short Bs[2][16384];

  const int seg = (int)blockIdx.x >= split;
  const GCfg cfg = seg ? c1 : c0;
  const int o = (int)blockIdx.x - (seg ? split : 0);
  const int nseg = seg ? ((int)gridDim.x - split) : split;
  const int qq = nseg >> 3;
  const int g = (o & 7) * qq + (o >> 3);
  const int ybl = g % cfg.ny; int t1 = g / cfg.ny;
  const int xbl = t1 % cfg.nx; const int kc = t1 / cfg.nx;

  const int M = cfg.M, lda = cfg.lda, ldb = cfg.ldb;
  const unsigned short* Ab = cfg.A + (size_t)kc * cfg.aKC;
  const unsigned short* Bb = cfg.B + (size_t)kc * cfg.bKC;

  const int tid = threadIdx.x, lane = tid & 63, wid = tid >> 6;  // 8 waves
  const int wm = wid >> 2, wn = wid & 3;
  const int m_base = ybl * 256, n_base = xbl * 256;
  const int fr = lane & 15, qk = lane >> 4;
  const int swz0 = ((qk ^ (fr & 7)) << 3);
  const int swz1 = (((4 + qk) ^ (fr & 7)) << 3);

  const int srow = lane >> 3;
  const int sc8 = (((lane & 7) ^ srow) << 3);
  const unsigned short* aS[2][2];
  const unsigned short* bS[2][2];
#pragma unroll
  for (int h = 0; h < 2; ++h)
#pragma unroll
    for (int j = 0; j < 2; ++j) {
      int rm = m_base + h * 128 + j * 64 + wid * 8 + srow;
      rm = rm < M ? rm : M - 1;                       // clamp; clamped rows never stored
      aS[h][j] = Ab + (size_t)rm * lda + sc8;
      bS[h][j] = Bb + (size_t)(n_base + h * 128 + j * 64 + wid * 8 + srow) * ldb + sc8;
    }
  // LDS byte bases for this wave's staging slots (wave-uniform)
  const unsigned aL = ldsOff(&As[0][0]) + (unsigned)(wid * 1024);
  const unsigned bL = ldsOff(&Bs[0][0]) + (unsigned)(wid * 1024);

  short8 a0[4][2], a1[4][2], b0[2][2], b1[2][2];
  f32x4 acc[8][4] = {};

  const int NT = cfg.K >> 6;    // K-tiles (even, >= 2)
  const int NIT = NT >> 1;      // tile pairs

  // ---- prologue: B(t0), A(t0) -> buf0; B(t1) -> buf1. 12 issues; drain 8 oldest ----
  STB8(0, 0, 0) STB8(0, 1, 0) STA8(0, 0, 0) STA8(0, 1, 0)
  STB8(1, 0, 64) STB8(1, 1, 64)
  asm volatile("s_waitcnt vmcnt(4)" ::: "memory");
  __builtin_amdgcn_s_barrier();

  // ---- main loop: exactly 2 gloads per phase; vmcnt(4) at ph4/ph8 ----
  for (int it = 0; it < NIT - 1; ++it) {
    const int t1k = (2 * it + 1) << 6;
    const int t2k = (2 * it + 2) << 6;
    const int t3k = (2 * it + 3) << 6;
    LDA8(a0, 0, 0) LDB8(b0, 0, 0) STA8(1, 0, t1k)
    ph_pre(); MMQ(a0, 0, b0, 0) ph_post();
    LDB8(b1, 0, 1) STA8(1, 1, t1k)
    ph_pre(); MMQ(a0, 0, b1, 1) ph_post();
    LDA8(a1, 0, 1) STB8(0, 0, t2k)
    ph_pre(); MMQ(a1, 1, b1, 1) ph_post();
    STB8(0, 1, t2k)
    ph_pre(); MMQ(a1, 1, b0, 0) ph_post_vm4();
    LDA8(a0, 1, 0) LDB8(b0, 1, 0) STA8(0, 0, t2k)
    ph_pre(); MMQ(a0, 0, b0, 0) ph_post();
    LDB8(b1, 1, 1) STA8(0, 1, t2k)
    ph_pre(); MMQ(a0, 0, b1, 1) ph_post();
    LDA8(a1, 1, 1) STB8(1, 0, t3k)
    ph_pre(); MMQ(a1, 1, b1, 1) ph_post();
    STB8(1, 1, t3k)
    ph_pre(); MMQ(a1, 1, b0, 0) ph_post_vm4();
  }

  // ---- peeled final pair (also the whole loop when NT==2) ----
  {
    const int tlk = (NT - 1) << 6;
    LDA8(a0, 0, 0) LDB8(b0, 0, 0) STA8(1, 0, tlk)
    ph_pre(); MMQ(a0, 0, b0, 0) ph_post();
    LDB8(b1, 0, 1) STA8(1, 1, tlk)
    ph_pre(); MMQ(a0, 0, b1, 1) ph_post();
    LDA8(a1, 0, 1)
    ph_pre(); MMQ(a1, 1, b1, 1) ph_post();
    ph_pre(); MMQ(a1, 1, b0, 0) ph_post_vm0();       // all staging landed
    LDA8(a0, 1, 0) LDB8(b0, 1, 0)
    ph_pre(); MMQ(a0, 0, b0, 0) ph_post();
    LDB8(b1, 1, 1)
    ph_pre(); MMQ(a0, 0, b1, 1) ph_post();
    LDA8(a1, 1, 1)
    ph_pre(); MMQ(a1, 1, b1, 1) ph_post();
    ph_pre(); MMQ(a1, 1, b0, 0)
    __builtin_amdgcn_s_setprio(0);
  }

  // ---- epilogue ----
  const size_t cOff = (size_t)kc * cfg.cKC;
  const int ldc = cfg.ldc;
  const int rq4 = qk * 4;
#pragma unroll
  for (int mi = 0; mi < 8; ++mi) {
#pragma unroll
    for (int ni = 0; ni < 4; ++ni) {
      int col = n_base + wn * 64 + ni * 16 + fr;
#pragma unroll
      for (int i = 0; i < 4; ++i) {
        int row = m_base + wm * 128 + mi * 16 + rq4 + i;
        if (row < M) {
          float val = acc[mi][ni][i];
          size_t off;
          if constexpr (PVF)       // ctx'[h=kc&7][(b=kc>>3)*NQ + row][col]
            off = (size_t)(kc & 7) * cfg.cKC
                + ((size_t)(kc >> 3) * NQ + row) * 1024 + col;
          else if constexpr (HB)
            off = (size_t)(col >> 10) * cfg.cKC + (size_t)row * ldc + (col & 1023);
          else
            off = cOff + (size_t)row * ldc + col;
          if constexpr (C_BF16) ((unsigned short*)cfg.C)[off] = f2bf(val);
          else                  ((float*)cfg.C)[off] = val;
        }
      }
    }
  }
}

// ---------- 128x128 single-buffer engine (score) — builtin gload ----------
template<bool C_BF16>
__global__ __launch_bounds__(256, 2) void k_gemm3(
    const unsigned short* __restrict__ A, const unsigned short* __restrict__ B,
    void* __restrict__ Cptr,
    int M, int K, int lda, int ldb, int ldc,
    int nx, int ny, int ZBH,
    long aSB, long aSH, long bSB, long bSH, long cSB, long cSH,
    long aKC, long bKC, long cKC) {
  __shared__ unsigned short As[8192];
  __shared__ unsigned short Bs[8192];

  const int nblk = gridDim.x;
  const int qq = nblk >> 3, rr = nblk & 7;
  int g;
  { const int o = blockIdx.x, xcd = o & 7, i = o >> 3;
    g = (xcd < rr ? xcd * (qq + 1) : rr * (qq + 1) + (xcd - rr) * qq) + i; }
  const int ybl = g % ny; int t1 = g / ny;
  const int xbl = t1 % nx; const int zz = t1 / nx;
  const int kc = zz / ZBH, bh = zz % ZBH;
  const int zb = bh >> 3, zh = bh & 7;

  const unsigned short* Ab = A + (size_t)zb * aSB + (size_t)zh * aSH + (size_t)kc * aKC;
  const unsigned short* Bb = B + (size_t)zb * bSB + (size_t)zh * bSH + (size_t)kc * bKC;

  const int tid = threadIdx.x, lane = tid & 63, wid = tid >> 6;
  const int wm = wid >> 1, wn = wid & 1;
  const int m_base = ybl * 128, n_base = xbl * 128;

  const int r0 = wid * 32 + (lane >> 3);
  const int sc8 = (((lane & 7) ^ (lane >> 3)) << 3);
  const unsigned short* aSrc[4];
  const unsigned short* bSrc[4];
#pragma unroll
  for (int p = 0; p < 4; ++p) {
    int rm = m_base + r0 + p * 8; rm = rm < M ? rm : M - 1;
    aSrc[p] = Ab + (size_t)rm * lda + sc8;
    bSrc[p] = Bb + (size_t)(n_base + r0 + p * 8) * ldb + sc8;
  }

  const int fr = lane & 15;
  const int qk = lane >> 4;
  f32x4 acc[4][4] = {};

  for (int k0 = 0; k0 < K; k0 += 64) {
#pragma unroll
    for (int p = 0; p < 4; ++p) gload16(aSrc[p] + k0, &As[wid * 2048 + p * 512]);
#pragma unroll
    for (int p = 0; p < 4; ++p) gload16(bSrc[p] + k0, &Bs[wid * 2048 + p * 512]);
    __syncthreads();
#pragma unroll
    for (int kk = 0; kk < 2; ++kk) {
      short8 af[4], bfr[4];
#pragma unroll
      for (int mi = 0; mi < 4; ++mi) {
        int row = wm * 64 + mi * 16 + fr;
        int swz = ((kk * 4 + qk) ^ (row & 7)) << 3;
        af[mi] = *reinterpret_cast<const short8*>(&As[row * 64 + swz]);
      }
#pragma unroll
      for (int ni = 0; ni < 4; ++ni) {
        int row = wn * 64 + ni * 16 + fr;
        int swz = ((kk * 4 + qk) ^ (row & 7)) << 3;
        bfr[ni] = *reinterpret_cast<const short8*>(&Bs[row * 64 + swz]);
      }
#pragma unroll
      for (int mi = 0; mi < 4; ++mi)
#pragma unroll
        for (int ni = 0; ni < 4; ++ni)
          acc[mi][ni] = __builtin_amdgcn_mfma_f32_16x16x32_bf16(af[mi], bfr[ni], acc[mi][ni], 0, 0, 0);
    }
    __syncthreads();
  }

  const size_t cOff = (size_t)zb * cSB + (size_t)zh * cSH + (size_t)kc * cKC;
  const int rq = qk * 4;
#pragma unroll
  for (int mi = 0; mi < 4; ++mi) {
#pragma unroll
    for (int ni = 0; ni < 4; ++ni) {
      int col = n_base + wn * 64 + ni * 16 + fr;
#pragma unroll
      for (int i = 0; i < 4; ++i) {
        int row = m_base + wm * 64 + mi * 16 + rq + i;
        if (row < M) {
          float val = acc[mi][ni][i];
          size_t off = cOff + (size_t)row * ldc + col;
          if constexpr (C_BF16) ((unsigned short*)Cptr)[off] = f2bf(val);
          else                  ((float*)Cptr)[off] = val;
        }
      }
    }
  }
}

// ======== fused midsection: V-transpose (blocks [0,8192)) + masked softmax ========
#define S_PART ((size_t)64 * NQ * NKK)
__global__ __launch_bounds__(256) void k_mid(
    const unsigned short* __restrict__ Vbase, unsigned short* __restrict__ Vt,
    const float* __restrict__ S, unsigned short* __restrict__ P,
    const int* __restrict__ mask) {
  __shared__ unsigned short tile[32][34];
  int blk = blockIdx.x;
  if (blk < 8192) {
    // ---- V transpose: KVb' V-chunk [8+h][b*128+key][1024 d] -> Vt[bh][d][key] ----
    int z = blk >> 7, b = z >> 3, h = z & 7;
    int d0 = (blk & 31) * 32, k0 = ((blk >> 5) & 3) * 32;
    const unsigned short* in = Vbase + ((size_t)h << 20) + (size_t)b * NKK * 1024;
    unsigned short* out = Vt + (size_t)z * DH * NKK;
    {
      int rr = threadIdx.x >> 3, c4 = (threadIdx.x & 7) << 2;
      ushort4 v = *reinterpret_cast<const ushort4*>(&in[(size_t)(k0 + rr) * 1024 + d0 + c4]);
      tile[rr][c4] = v.x; tile[rr][c4 + 1] = v.y;
      tile[rr][c4 + 2] = v.z; tile[rr][c4 + 3] = v.w;
    }
    __syncthreads();
    {
      int cc = threadIdx.x >> 3, r4 = (threadIdx.x & 7) << 2;
      ushort4 w;
      w.x = tile[r4][cc];     w.y = tile[r4 + 1][cc];
      w.z = tile[r4 + 2][cc]; w.w = tile[r4 + 3][cc];
      *reinterpret_cast<ushort4*>(&out[(size_t)(d0 + cc) * NKK + k0 + r4]) = w;
    }
    return;
  }
  // ---- masked softmax over 128 keys (reduces 2 split-K partials), 1 wave/row ----
  int row = (blk - 8192) * 4 + (threadIdx.x >> 6);
  if (row >= BB * HH * NQ) return;
  int lane = threadIdx.x & 63;
  int b = row / (HH * NQ);
  const float* s = S + (size_t)row * NKK;
  float s0 = (s[lane]      + s[lane + S_PART])      * 0.03125f;
  float s1 = (s[lane + 64] + s[lane + 64 + S_PART]) * 0.03125f;
  const int* mrow = mask + b * NKK;
  if (mrow[lane] == 0)      s0 = -1e30f;
  if (mrow[lane + 64] == 0) s1 = -1e30f;
  float mx = fmaxf(s0, s1);
#pragma unroll
  for (int d = 32; d; d >>= 1) mx = fmaxf(mx, __shfl_xor(mx, d));
  float e0 = __expf(s0 - mx), e1 = __expf(s1 - mx);
  float sum = e0 + e1;
#pragma unroll
  for (int d = 32; d; d >>= 1) sum += __shfl_xor(sum, d);
  float inv = 1.0f / sum;
  P[(size_t)row * NKK + lane]      = f2bf(e0 * inv);
  P[(size_t)row * NKK + lane + 64] = f2bf(e1 * inv);
}

// --- fused split-K reduce (bf16 partials) + residual + LayerNorm over 1024, 1 block/row ---
__global__ __launch_bounds__(256) void k_layernorm_red(
    const unsigned short* __restrict__ Parts, const float* __restrict__ resid,
    const float* __restrict__ gamma, const float* __restrict__ beta,
    float* __restrict__ out, int M) {
  int row = blockIdx.x;
  int tid = threadIdx.x;
  const size_t stride = (size_t)M * DI;
  const unsigned short* p = Parts + (size_t)row * DI;
  const float* r = resid + (size_t)row * DI;
  float v[4], sum = 0.f, sq = 0.f;
#pragma unroll
  for (int i = 0; i < 4; ++i) {
    int c = tid + i * 256;
    float acc = r[c];
#pragma unroll
    for (int k = 0; k < KSPLIT; ++k)
      acc += __uint_as_float((unsigned)p[k * stride + c] << 16);
    v[i] = acc; sum += acc; sq += acc * acc;
  }
#pragma unroll
  for (int d = 32; d; d >>= 1) { sum += __shfl_xor(sum, d); sq += __shfl_xor(sq, d); }
  __shared__ float ssum[4], ssq[4];
  int w = tid >> 6;
  if ((tid & 63) == 0) { ssum[w] = sum; ssq[w] = sq; }
  __syncthreads();
  sum = ssum[0] + ssum[1] + ssum[2] + ssum[3];
  sq  = ssq[0]  + ssq[1]  + ssq[2]  + ssq[3];
  float mean = sum * (1.0f / DI);
  float var  = sq * (1.0f / DI) - mean * mean;
  float rstd = rsqrtf(var + 1e-5f);
  float* o = out + (size_t)row * DI;
#pragma unroll
  for (int i = 0; i < 4; ++i) {
    int c = tid + i * 256;
    o[c] = (v[i] - mean) * rstd * gamma[c] + beta[c];
  }
}

extern "C" void kernel_launch(void* const* d_in, const int* in_sizes, int n_in,
                              void* d_out, int out_size, void* d_ws, size_t ws_size,
                              hipStream_t stream) {
  const float* img   = (const float*)d_in[0];
  const float* sent  = (const float*)d_in[1];
  const int*   mask  = (const int*)d_in[2];
  const float* Wq    = (const float*)d_in[3];
  const float* Wk    = (const float*)d_in[4];
  const float* Wv    = (const float*)d_in[5];
  const float* Wo    = (const float*)d_in[6];
  const float* gamma = (const float*)d_in[7];
  const float* beta  = (const float*)d_in[8];
  float* out = (float*)d_out;

  // ---- workspace map (lifetime-aliased; peak ~110.4 MB) ----
  // Qb'[8 h][1568][1024] | KVb'[16 chunk][1024][1024] | WoT'[8 kc][1024][1024]
  // ctx'[8 h][1568][1024] | Oac[8 kc][1568][1024] bf16
  char* ws = (char*)d_ws;
  unsigned short* WoT   = (unsigned short*)(ws);                  // s0-s7
  unsigned short* WkvT  = (unsigned short*)(ws + 16777216);       // s0-s2
  unsigned short* Vt    = (unsigned short*)(ws + 16777216);       // s5-s6 (over WkvT)
  unsigned short* Oac   = (unsigned short*)(ws + 16777216);       // s7-s8 (25.7 MB bf16)
  float*          S2    = (float*)         (ws + 33554432);       // s4-s5
  unsigned short* P     = (unsigned short*)(ws + 46399488);       // s5-s6
  unsigned short* Qb    = (unsigned short*)(ws + 49610752);       // s1-s4
  unsigned short* KVb   = (unsigned short*)(ws + 75300864);       // s2-s5
  unsigned short* ctx   = (unsigned short*)(ws + 75300864);       // s6-s7
  unsigned short* WqT   = (unsigned short*)(ws + 75300864);       // s0-s1
  unsigned short* imgB  = (unsigned short*)(ws + 92078080);       // s0-s1
  unsigned short* sentB = (unsigned short*)(ws + 108855296);      // s0-s2

  dim3 tb(256);
  dim3 tb8(512);

  // s0) all transposes + input converts, one launch (WoT kc-blocked)
  k_prep<<<dim3(8336), tb, 0, stream>>>(Wq, Wk, Wv, Wo, img, sent,
                                        WqT, WkvT, WoT, imgB, sentB);

  // s1+s2) Q-proj (HB -> Qb') and KV-proj (HB -> KVb'), one launch
  GCfg cfgQ  = { imgB,  WqT,  Qb,  MTOT,     DI, DI, DI, 1024, 32, 7, 0, 0, (long)CHK };
  GCfg cfgKV = { sentB, WkvT, KVb, BB * NKK, DL, DL, DL, 1024, 64, 4, 0, 0, (long)KVCHK };
  k_gemm8<true, true, false><<<dim3(224 + 256), tb8, 0, stream>>>(cfgQ, cfgKV, 224);

  // s4) S2[kc][b][h][196][128] = Q_bh[:,kc] @ K_bh[:,kc]^T  (split-K=2)
  k_gemm3<false><<<dim3(2 * 1 * 128), tb, 0, stream>>>(
      Qb, KVb, S2, NQ, DH / 2, 1024, 1024, NKK,
      1, 2, 64,
      (long)NQ * 1024, (long)CHK,
      (long)NKK * 1024, (long)KVCHK,
      (long)HH * NQ * NKK, (long)NQ * NKK,
      (long)(DH / 2), (long)(DH / 2), (long)64 * NQ * NKK);

  // s5) fused: V -> Vt transpose (8192 blocks) + P = softmax(sum(S2)/32) (3136 blocks)
  k_mid<<<dim3(8192 + (BB * HH * NQ) / 4), tb, 0, stream>>>(
      KVb + ((size_t)8 << 20), Vt, S2, P, mask);

  // s6) ctx'[h][b*196+q][1024] = P_bh @ V_bh  — gemm8 PVF path, 256 blocks, NT=2
  GCfg cfgPV = { P, Vt, ctx, NQ, NKK, NKK, NKK, 1024, 4, 1,
                 (long)NQ * NKK, (long)DH * NKK, (long)CHK };
  k_gemm8<true, false, true><<<dim3(256), tb8, 0, stream>>>(cfgPV, cfgPV, 256);

  // s7) out-proj split-K: Oac[kc] = ctx'[kc] @ WoT'[kc]^T  — bf16 partials
  GCfg cfgO = { ctx, WoT, Oac, MTOT, HD / KSPLIT, 1024, 1024, DI, 4, 7,
                (long)CHK, (long)KVCHK, (long)CHK };
  k_gemm8<true, false, false><<<dim3(224), tb8, 0, stream>>>(cfgO, cfgO, 224);

  // s8) fused reduce(8 bf16 partials) + residual + LayerNorm -> d_out
  k_layernorm_red<<<dim3(BB * NQ), tb, 0, stream>>>(Oac, img, gamma, beta, out, BB * NQ);
}